// Round 9
// baseline (97.126 us; speedup 1.0000x reference)
//
#include <hip/hip_runtime.h>

#define IN_DIM 256
#define OUT_DIM 64
#define NEG_SLOPE 0.01f
#define CHUNK 1024   // edges per kA_scatter block (782 blocks -> real TLP)
#define KPT (CHUNK / 256)

typedef __attribute__((ext_vector_type(8))) short short8v;   // 8 bf16 (4 VGPRs)
typedef __attribute__((ext_vector_type(4))) float float4v;   // MFMA C/D

// fp32 -> bf16 round-to-nearest-even
__device__ __forceinline__ unsigned short f2bf(float f) {
    unsigned u = __float_as_uint(f);
    return (unsigned short)((u + 0x7FFFu + ((u >> 16) & 1u)) >> 16);
}
__device__ __forceinline__ float bf2f(unsigned short u) {
    return __uint_as_float((unsigned)u << 16);
}

// ---------------- K0: zero bucket counters/cursors + convert W to bf16 -----
__global__ void k_init(const float* __restrict__ W, unsigned short* __restrict__ Wb,
                       int* __restrict__ bc, int* __restrict__ cursor) {
    int i = blockIdx.x * blockDim.x + threadIdx.x;
    if (i < OUT_DIM * IN_DIM) Wb[i] = f2bf(W[i]);
    if (i < 256) { bc[i] = 0; cursor[i] = 0; }
}

// ---------------- K1: MFMA projection + fused el/er + fused dst-count ------
// One wave per 16-row tile, 4 x mfma_f32_16x16x32_bf16 (16 rows x 64 cols).
// C/D layout (HW-verified): col = lane&15, row = (lane>>4)*4 + reg.
// (a) all 16 h-float4 preloaded into regs -> 16 loads in flight;
// (b) Wb staged in LDS with 16B-slot XOR swizzle -> conflict-free b128 reads.
__global__ __launch_bounds__(256, 3) void k1_mfma_count(
        const float* __restrict__ h, const unsigned short* __restrict__ Wb,
        const float* __restrict__ a, const int* __restrict__ dst,
        unsigned short* __restrict__ zb, float* __restrict__ el, float* __restrict__ er,
        int* __restrict__ bc, int M, int E) {
    __shared__ uint4 wlds[2048];          // 32 KB: W bf16, swizzled 16B slots
    __shared__ int hist[256];
    hist[threadIdx.x] = 0;

    // stage Wb -> LDS: slot = row*32 + (col ^ (row&7)); coalesced global read
    #pragma unroll
    for (int k = 0; k < 8; ++k) {
        int c = threadIdx.x + k * 256;
        int row = c >> 5, col = c & 31;
        wlds[(row << 5) | (col ^ (row & 7))] = ((const uint4*)Wb)[c];
    }
    __syncthreads();

    const int lane = threadIdx.x & 63;
    const int wid  = (blockIdx.x * 256 + threadIdx.x) >> 6;
    const int r0 = wid * 16;

    if (r0 < M) {
        const int lrow = lane & 15;
        const int kgrp = lane >> 4;
        const int k0   = kgrp * 8;
        const int swz  = lrow & 7;

        const float* __restrict__ hrow = h + (size_t)(r0 + lrow) * IN_DIM;

        // burst-load the whole per-lane h strip (16 x dwordx4 in flight)
        float4 hreg[16];
        #pragma unroll
        for (int s = 0; s < 8; ++s) {
            hreg[2 * s]     = *(const float4*)(hrow + s * 32 + k0);
            hreg[2 * s + 1] = *(const float4*)(hrow + s * 32 + k0 + 4);
        }

        float4v acc[4];
        #pragma unroll
        for (int n = 0; n < 4; ++n) acc[n] = (float4v){0.f, 0.f, 0.f, 0.f};

        #pragma unroll
        for (int s = 0; s < 8; ++s) {
            float4 ha = hreg[2 * s], hb = hreg[2 * s + 1];
            short8v afrag;
            afrag[0] = (short)f2bf(ha.x); afrag[1] = (short)f2bf(ha.y);
            afrag[2] = (short)f2bf(ha.z); afrag[3] = (short)f2bf(ha.w);
            afrag[4] = (short)f2bf(hb.x); afrag[5] = (short)f2bf(hb.y);
            afrag[6] = (short)f2bf(hb.z); afrag[7] = (short)f2bf(hb.w);
            #pragma unroll
            for (int n = 0; n < 4; ++n) {
                const int slot = ((n * 16 + lrow) << 5) | ((s * 4 + kgrp) ^ swz);
                short8v bfrag = *(const short8v*)&wlds[slot];
                acc[n] = __builtin_amdgcn_mfma_f32_16x16x32_bf16(afrag, bfrag, acc[n], 0, 0, 0);
            }
        }

        float al4[4], ar4[4];
        #pragma unroll
        for (int n = 0; n < 4; ++n) {
            al4[n] = a[n * 16 + lrow];
            ar4[n] = a[OUT_DIM + n * 16 + lrow];
        }
        #pragma unroll
        for (int j = 0; j < 4; ++j) {
            const int row = r0 + kgrp * 4 + j;
            float vl = 0.f, vr = 0.f;
            #pragma unroll
            for (int n = 0; n < 4; ++n) {
                float v = acc[n][j];
                zb[(size_t)row * OUT_DIM + n * 16 + lrow] = f2bf(v);
                vl += v * al4[n];
                vr += v * ar4[n];
            }
            #pragma unroll
            for (int m = 8; m >= 1; m >>= 1) {
                vl += __shfl_xor(vl, m, 64);
                vr += __shfl_xor(vr, m, 64);
            }
            if (lrow == 0) { el[row] = vl; er[row] = vr; }
        }
    }

    // ---- fused bucket count (bucket = dst>>8) ----
    __syncthreads();
    const int stride = gridDim.x * 256;
    for (int i = blockIdx.x * 256 + threadIdx.x; i < E; i += stride)
        atomicAdd(&hist[dst[i] >> 8], 1);
    __syncthreads();
    if (hist[threadIdx.x]) atomicAdd(&bc[threadIdx.x], hist[threadIdx.x]);
}

// ---------------- kA_scatter: partition edges into buckets, coalesced -------
// 782 blocks (CHUNK=1024). Self-computes bucket starts from bc (LDS scan).
// LDS hist -> scan -> rank -> stage packed (dst<<16|src) in bucket order ->
// reserve global runs (1 atomic/bucket) -> coalesced run writes.
__global__ __launch_bounds__(256) void kA_scatter(
        const int* __restrict__ src, const int* __restrict__ dst,
        const int* __restrict__ bc, int* __restrict__ cursor,
        unsigned* __restrict__ bucketbuf, int E, int nbuck) {
    __shared__ unsigned stag[CHUNK];
    __shared__ int bsc[256], cnt[256], lofs[256], lcur[256], tb[256];
    const int t = threadIdx.x;
    const int base = blockIdx.x * CHUNK;
    const int n = min(CHUNK, E - base);

    // self-scan: bstart (exclusive prefix of bc) for this thread's bucket
    int bv = (t < nbuck) ? bc[t] : 0;
    bsc[t] = bv;
    cnt[t] = 0;
    __syncthreads();
    for (int off = 1; off < 256; off <<= 1) {
        int add = (t >= off) ? bsc[t - off] : 0;
        __syncthreads();
        bsc[t] += add;
        __syncthreads();
    }
    const int bstart_t = bsc[t] - bv;   // exclusive

    int es[KPT], ed[KPT];
    #pragma unroll
    for (int k = 0; k < KPT; ++k) {
        int p = t + k * 256;
        if (p < n) {
            es[k] = src[base + p];
            ed[k] = dst[base + p];
            atomicAdd(&cnt[ed[k] >> 8], 1);
        }
    }
    __syncthreads();

    // exclusive scan of cnt -> lofs
    lofs[t] = cnt[t];
    __syncthreads();
    for (int off = 1; off < 256; off <<= 1) {
        int add = (t >= off) ? lofs[t - off] : 0;
        __syncthreads();
        lofs[t] += add;
        __syncthreads();
    }
    lofs[t] -= cnt[t];
    __syncthreads();

    // reserve global runs; translate staging position -> global
    {
        int c = cnt[t];
        int g = c ? atomicAdd(&cursor[t], c) : 0;
        tb[t] = bstart_t + g - lofs[t];
    }
    lcur[t] = lofs[t];
    __syncthreads();

    // rank + stage in bucket-sorted order
    #pragma unroll
    for (int k = 0; k < KPT; ++k) {
        int p = t + k * 256;
        if (p < n) {
            int b = ed[k] >> 8;
            int pos = atomicAdd(&lcur[b], 1);
            stag[pos] = ((unsigned)ed[k] << 16) | (unsigned)es[k];
        }
    }
    __syncthreads();

    // coalesced run writes (consecutive p -> same bucket run)
    #pragma unroll
    for (int k = 0; k < KPT; ++k) {
        int p = t + k * 256;
        if (p < n) {
            unsigned v = stag[p];
            int b = v >> 24;                 // = dst>>8
            bucketbuf[tb[b] + p] = v;
        }
    }
}

// ---------------- kB_build: per-bucket local CSR + ends --------------------
// One block per bucket (256 local nodes); self-computes its bucket start.
__global__ __launch_bounds__(256) void kB_build(
        const unsigned* __restrict__ bucketbuf, const int* __restrict__ bc,
        int* __restrict__ csr_src, int* __restrict__ ends, int N, int nbuck) {
    __shared__ int sc[256], lcnt[256], lofs[256], lcur[256];
    __shared__ int s_start;
    const int b = blockIdx.x, t = threadIdx.x;

    int bv = (t < nbuck) ? bc[t] : 0;
    sc[t] = bv;
    lcnt[t] = 0;
    __syncthreads();
    for (int off = 1; off < 256; off <<= 1) {
        int add = (t >= off) ? sc[t - off] : 0;
        __syncthreads();
        sc[t] += add;
        __syncthreads();
    }
    if (t == b) s_start = sc[t] - bv;       // exclusive prefix at own bucket
    __syncthreads();

    const int start = s_start;
    const int cnt = bc[b];
    const int node0 = b << 8;
    const int nloc = min(256, N - node0);

    for (int i = t; i < cnt; i += 256)
        atomicAdd(&lcnt[(bucketbuf[start + i] >> 16) & 255], 1);
    __syncthreads();

    // inclusive scan -> lofs
    lofs[t] = lcnt[t];
    __syncthreads();
    for (int off = 1; off < 256; off <<= 1) {
        int add = (t >= off) ? lofs[t - off] : 0;
        __syncthreads();
        lofs[t] += add;
        __syncthreads();
    }
    if (t < nloc) ends[node0 + t] = start + lofs[t];   // global inclusive end
    lcur[t] = lofs[t] - lcnt[t];                        // local exclusive start
    __syncthreads();

    for (int i = t; i < cnt; i += 256) {
        unsigned v = bucketbuf[start + i];
        int node = (v >> 16) & 255;
        int pos = atomicAdd(&lcur[node], 1);
        csr_src[start + pos] = (int)(v & 0xFFFFu);
    }
}

// ---------------- K5: per-node softmax + gather-aggregate (no atomics) ------
// One wave per dst node. Paired-edge gather: lanes 0-31 take even edges,
// lanes 32-63 odd edges; each lane loads a uint (2 bf16 cols) -> one
// instruction fetches two 128B z-rows. Final shfl_xor(32) folds halves;
// lanes 0-31 write coalesced float2.
__global__ __launch_bounds__(256) void k5_node(
        const int* __restrict__ csr_src, const int* __restrict__ ends,
        const float* __restrict__ el, const float* __restrict__ er,
        const unsigned short* __restrict__ zb, float* __restrict__ out, int N) {
    const int lane = threadIdx.x & 63;
    const int node = blockIdx.x * 4 + (threadIdx.x >> 6);
    if (node >= N) return;

    const int start = (node == 0) ? 0 : ends[node - 1];
    const int end   = ends[node];
    const int deg   = end - start;
    const int half  = lane >> 5;        // 0: even edges, 1: odd edges
    const int lh    = lane & 31;        // col pair (2*lh, 2*lh+1)

    float rlo = 0.f, rhi = 0.f;         // col-pair result (lanes 0-31 valid)

    if (deg > 0 && deg <= 64) {
        const float er_i = er[node];
        int   s0 = 0;
        float m  = -3.4e38f;
        float e0 = 0.0f;
        if (lane < deg) {
            s0 = csr_src[start + lane];
            float x = el[s0] + er_i;
            e0 = fmaxf(x, NEG_SLOPE * x);
            m  = e0;
        }
        #pragma unroll
        for (int msk = 32; msk; msk >>= 1) m = fmaxf(m, __shfl_xor(m, msk, 64));
        float ex0 = (lane < deg) ? __expf(e0 - m) : 0.0f;
        float sum = ex0;
        #pragma unroll
        for (int msk = 32; msk; msk >>= 1) sum += __shfl_xor(sum, msk, 64);
        const float inv = 1.0f / sum;

        const int npairs = (deg + 1) >> 1;
        float2 acc0 = {0.f, 0.f}, acc1 = {0.f, 0.f},
               acc2 = {0.f, 0.f}, acc3 = {0.f, 0.f};
        int p = 0;
        for (; p + 4 <= npairs; p += 4) {
            #pragma unroll
            for (int q = 0; q < 4; ++q) {
                int e  = 2 * (p + q) + half;
                int cl = (e < deg) ? e : (deg - 1);
                float wv = __shfl(ex0, cl, 64);
                int   sv = __shfl(s0,  cl, 64);
                if (e >= deg) wv = 0.0f;
                unsigned u = *(const unsigned*)(zb + (size_t)sv * OUT_DIM + lh * 2);
                float zl = bf2f((unsigned short)(u & 0xFFFFu));
                float zh = bf2f((unsigned short)(u >> 16));
                if (q == 0) { acc0.x += wv * zl; acc0.y += wv * zh; }
                else if (q == 1) { acc1.x += wv * zl; acc1.y += wv * zh; }
                else if (q == 2) { acc2.x += wv * zl; acc2.y += wv * zh; }
                else { acc3.x += wv * zl; acc3.y += wv * zh; }
            }
        }
        for (; p < npairs; ++p) {
            int e  = 2 * p + half;
            int cl = (e < deg) ? e : (deg - 1);
            float wv = __shfl(ex0, cl, 64);
            int   sv = __shfl(s0,  cl, 64);
            if (e >= deg) wv = 0.0f;
            unsigned u = *(const unsigned*)(zb + (size_t)sv * OUT_DIM + lh * 2);
            acc0.x += wv * bf2f((unsigned short)(u & 0xFFFFu));
            acc0.y += wv * bf2f((unsigned short)(u >> 16));
        }
        rlo = ((acc0.x + acc1.x) + (acc2.x + acc3.x));
        rhi = ((acc0.y + acc1.y) + (acc2.y + acc3.y));
        rlo += __shfl_xor(rlo, 32, 64);
        rhi += __shfl_xor(rhi, 32, 64);
        rlo *= inv; rhi *= inv;
    } else if (deg > 64) {
        // generic path (vanishingly rare at avg deg 16)
        const float er_i = er[node];
        float e0 = 0.0f, e1 = 0.0f;
        int   s0 = 0,    s1 = 0;
        float m = -3.4e38f;
        int t = 0;
        for (int j = start + lane; j < end; j += 64, ++t) {
            int s = csr_src[j];
            float x = el[s] + er_i;
            float e = fmaxf(x, NEG_SLOPE * x);
            if (t == 0) { e0 = e; s0 = s; }
            else if (t == 1) { e1 = e; s1 = s; }
            m = fmaxf(m, e);
        }
        #pragma unroll
        for (int msk = 32; msk; msk >>= 1) m = fmaxf(m, __shfl_xor(m, msk, 64));
        float sum = 0.0f;
        t = 0;
        for (int j = start + lane; j < end; j += 64, ++t) {
            float e;
            if (t == 0) e = e0;
            else if (t == 1) e = e1;
            else {
                int s = csr_src[j];
                float x = el[s] + er_i;
                e = fmaxf(x, NEG_SLOPE * x);
            }
            float ex = __expf(e - m);
            if (t == 0) e0 = ex; else if (t == 1) e1 = ex;
            sum += ex;
        }
        #pragma unroll
        for (int msk = 32; msk; msk >>= 1) sum += __shfl_xor(sum, msk, 64);
        const float inv = 1.0f / sum;

        float acc = 0.0f;
        for (int r = 0; r < deg; ++r) {
            int tt = r >> 6, owner = r & 63;
            int s; float ex;
            if (tt == 0)      { s = __shfl(s0, owner, 64); ex = __shfl(e0, owner, 64); }
            else if (tt == 1) { s = __shfl(s1, owner, 64); ex = __shfl(e1, owner, 64); }
            else {
                s = csr_src[start + r];
                float x = el[s] + er_i;
                float e = fmaxf(x, NEG_SLOPE * x);
                ex = __expf(e - m);
            }
            acc += ex * bf2f(zb[(size_t)s * OUT_DIM + lane]);
        }
        acc *= inv;
        rlo = __shfl(acc, 2 * lh, 64);
        rhi = __shfl(acc, 2 * lh + 1, 64);
    }

    if (lane < 32) {
        float2 o; o.x = rlo; o.y = rhi;
        *(float2*)(out + (size_t)node * OUT_DIM + lh * 2) = o;
    }
}

extern "C" void kernel_launch(void* const* d_in, const int* in_sizes, int n_in,
                              void* d_out, int out_size, void* d_ws, size_t ws_size,
                              hipStream_t stream) {
    const float* h   = (const float*)d_in[0];
    const float* W   = (const float*)d_in[1];
    const float* a   = (const float*)d_in[2];
    const int*   src = (const int*)d_in[3];
    const int*   dst = (const int*)d_in[4];
    float* out = (float*)d_out;

    const int N = in_sizes[0] / IN_DIM;     // 50000
    const int E = in_sizes[3];              // 800000
    const int nbuck = (N + 255) >> 8;       // 196

    // workspace layout (~13.4 MB)
    unsigned short* zb = (unsigned short*)d_ws;          // N*64 bf16 (6.4 MB)
    float* el   = (float*)(zb + (size_t)N * OUT_DIM);    // N
    float* er   = el + N;                                // N
    int*   ends = (int*)(er + N);                        // N (global inclusive ends)
    int*   csr_src = ends + N;                           // E
    unsigned* bucketbuf = (unsigned*)(csr_src + E);      // E
    int*   bc     = (int*)(bucketbuf + E);               // 256
    int*   cursor = bc + 256;                            // 256
    unsigned short* Wb = (unsigned short*)(cursor + 256); // 64*256 bf16 (32 KB, 16B-aligned)

    k_init<<<(OUT_DIM * IN_DIM + 255) / 256, 256, 0, stream>>>(W, Wb, bc, cursor);
    {
        const int waves = (N + 15) / 16;    // 3125 row-tiles
        k1_mfma_count<<<(waves + 3) / 4, 256, 0, stream>>>(h, Wb, a, dst, zb, el, er,
                                                           bc, N, E);
    }
    kA_scatter<<<(E + CHUNK - 1) / CHUNK, 256, 0, stream>>>(src, dst, bc, cursor,
                                                            bucketbuf, E, nbuck);
    kB_build<<<nbuck, 256, 0, stream>>>(bucketbuf, bc, csr_src, ends, N, nbuck);
    k5_node<<<(N + 3) / 4, 256, 0, stream>>>(csr_src, ends, el, er, zb, out, N);
}